// Round 11
// baseline (69.871 us; speedup 1.0000x reference)
//
#include <hip/hip_runtime.h>
#include <math.h>

// Problem constants: B=4, CIN=32, COUT=64, H=W=32, K=3, pad=1

typedef _Float16 half8 __attribute__((ext_vector_type(8)));
typedef float floatx4 __attribute__((ext_vector_type(4)));

// ---------------- workspace layout ----------------
// B_f16: [var 2][tap 9][n 128][chunk p 16][16B]  = 576 KB (L2-resident)
//   n = xy*64 + o (xy: 0=cos-weights, 1=sin-weights); position p holds
//   k-chunk q = p ^ (n & 7); k = q*8 + j, c = k>>2, feat = k&3
//   var 0 = hi, var 1 = lo*2048
// NOTE (R9 failure): B-lo CANNOT be dropped — ay abs-err ~3e-3 flips the
// atan2 branch cut at the ~50 pixels with ay~0, ax<0 -> 2pi absmax.
#define B_TAP_STRIDE (128 * 256)      // 32768
#define B_VSTRIDE (9u * 128 * 256)    // 294912

__global__ __launch_bounds__(256) void ring_prep_b(
    const float* __restrict__ probe, const float* __restrict__ outw,
    char* __restrict__ Bg) {
  int i = blockIdx.x * 256 + threadIdx.x;   // 18432 threads = 72 blocks
  int p = i & 15;
  int n = (i >> 4) & 127;
  int tap = i >> 11;
  int qd = p ^ (n & 7);
  int o = n & 63;
  int xy = n >> 6;
  half8 hi, lo;
#pragma unroll
  for (int hf = 0; hf < 2; ++hf) {
    int c = qd * 2 + hf;
    int idx = (c * 64 + o) * 9 + tap;       // ((c*COUT + o)*3 + k)*3 + l
    float th = probe[idx];
    float wvv = outw[idx];
    float sth, cth, sw, cw;
    __sincosf(th, &sth, &cth);
    __sincosf(wvv, &sw, &cw);
    float c3 = cth * fmaf(4.0f * cth, cth, -3.0f);
    float s3 = sth * fmaf(-4.0f * sth, sth, 3.0f);
    float m = xy ? sw : cw;
    float v4[4] = {0.75f * m * cth, 0.75f * m * sth, 0.25f * m * c3,
                   0.25f * m * s3};
#pragma unroll
    for (int f = 0; f < 4; ++f) {
      _Float16 hv = (_Float16)v4[f];
      hi[hf * 4 + f] = hv;
      lo[hf * 4 + f] = (_Float16)((v4[f] - (float)hv) * 2048.0f);
    }
  }
  size_t off = (((size_t)tap * 128 + n) * 16 + p) * 16;
  *(half8*)(Bg + off) = hi;
  *(half8*)(Bg + off + B_VSTRIDE) = lo;
}

// Block: one full (b,h) pixel row (32 px) x 64 n. 512 threads = 8 waves:
// wave wv -> wt = wv>>2 (pixel half), xy = (wv>>1)&1, og = wv&1.
// Waves (wt=0,*) and (wt=1,*) with equal (xy,og) read IDENTICAL B addresses
// -> L1 dedups, halving per-CU L2 B-traffic vs the 2-block R10 layout.
// A-tile features (fp16 hi + lo*2048) computed in-block into swizzled LDS:
// sA [var 2][r 3][colidx 34][p 16][16B]; chunk q = p ^ (colidx & 7).
// B (hi+lo) via explicit 2-stage register double-buffer from global/L2.
#define AL_OFF 26112   // 1632 * 16

__global__ __launch_bounds__(512, 2) void ring_mfma(
    const float* __restrict__ x, const char* __restrict__ Bg,
    float* __restrict__ out) {
  __shared__ __align__(16) char sA[52224];
  __shared__ float sEx[1024];  // [wt 2][og 2][n 16][m 16]

  int blk = blockIdx.x;  // (b*32 + h)*2 + oh
  int oh = blk & 1;
  int h = (blk >> 1) & 31;
  int b = blk >> 6;
  int tid = threadIdx.x;

  int lane = tid & 63;
  int wv = tid >> 6;
  int n16 = lane & 15;
  int quad = lane >> 4;
  int wt = wv >> 2;
  int xy = (wv >> 1) & 1;
  int og = wv & 1;

  // global n this lane's B column lives at; swizzle key n&7 == n16&7 since
  // xy*64, oh*32, og*16 are all 0 mod 8.  (wt-independent.)
  int n_global = xy * 64 + oh * 32 + og * 16 + n16;
  const char* bRow = Bg + (size_t)n_global * 256;
  const char* bRowL = bRow + B_VSTRIDE;
  int bkey = n16 & 7;
  int p0 = ((0 * 4 + quad) ^ bkey) * 16;
  int p1 = ((1 * 4 + quad) ^ bkey) * 16;
  int p2 = ((2 * 4 + quad) ^ bkey) * 16;
  int p3 = ((3 * 4 + quad) ^ bkey) * 16;

  // ---- prefetch tap 0's B fragments (in flight across the A-setup) ----
  half8 BcH0 = *(const half8*)(bRow + p0);
  half8 BcH1 = *(const half8*)(bRow + p1);
  half8 BcH2 = *(const half8*)(bRow + p2);
  half8 BcH3 = *(const half8*)(bRow + p3);
  half8 BcL0 = *(const half8*)(bRowL + p0);
  half8 BcL1 = *(const half8*)(bRowL + p1);
  half8 BcL2 = *(const half8*)(bRowL + p2);
  half8 BcL3 = *(const half8*)(bRowL + p3);

  // ---- compute A tile in-block: 1632 hi/lo unit pairs (3 r x 34 col x 16 p) ----
  for (int u = tid; u < 1632; u += 512) {
    int p = u & 15;
    int t = u >> 4;          // 0..101
    int colidx = t % 34;
    int r = t / 34;
    int q = p ^ (colidx & 7);
    int hs = h + r - 1;
    int wsx = colidx - 1;
    bool valid = ((unsigned)hs < 32u) && ((unsigned)wsx < 32u);
    half8 hi, lo;
#pragma unroll
    for (int hf = 0; hf < 2; ++hf) {
      int c = q * 2 + hf;
      float c1 = 1.0f, s1 = 0.0f;
      if (valid) {
        float pv = x[((b * 32 + c) * 32 + hs) * 32 + wsx];
        __sincosf(pv, &s1, &c1);
      }
      float c3 = c1 * fmaf(4.0f * c1, c1, -3.0f);
      float s3 = s1 * fmaf(-4.0f * s1, s1, 3.0f);
      float v4[4] = {c1, s1, c3, s3};
#pragma unroll
      for (int f = 0; f < 4; ++f) {
        _Float16 hv = (_Float16)v4[f];
        hi[hf * 4 + f] = hv;
        lo[hf * 4 + f] = (_Float16)((v4[f] - (float)hv) * 2048.0f);
      }
    }
    *(half8*)(sA + u * 16) = hi;            // var 0 section
    *(half8*)(sA + u * 16 + AL_OFF) = lo;   // var 1 section
  }

  floatx4 acc0 = {0.f, 0.f, 0.f, 0.f};   // Ah*Bh
  floatx4 acc1 = {0.f, 0.f, 0.f, 0.f};   // Al*Bh
  floatx4 acc2 = {0.f, 0.f, 0.f, 0.f};   // Ah*Bl

  __syncthreads();  // A tile visible; tap loop is barrier-free

#pragma unroll
  for (int tap = 0; tap < 9; ++tap) {
    // prefetch next tap's B (hi+lo) into the other buffer
    half8 BnH0, BnH1, BnH2, BnH3, BnL0, BnL1, BnL2, BnL3;
    if (tap < 8) {
      const char* bn = bRow + (size_t)(tap + 1) * B_TAP_STRIDE;
      const char* bnL = bn + B_VSTRIDE;
      BnH0 = *(const half8*)(bn + p0);
      BnH1 = *(const half8*)(bn + p1);
      BnH2 = *(const half8*)(bn + p2);
      BnH3 = *(const half8*)(bn + p3);
      BnL0 = *(const half8*)(bnL + p0);
      BnL1 = *(const half8*)(bnL + p1);
      BnL2 = *(const half8*)(bnL + p2);
      BnL3 = *(const half8*)(bnL + p3);
    }

    int dk = tap / 3;
    int l = tap - dk * 3;
    int colidx = wt * 16 + n16 + l;  // pixel-within-row + l; akey unchanged
    int akey = colidx & 7;           // by wt*16 since 16 % 8 == 0
    const char* aH = sA + (dk * 34 + colidx) * 256;
    const char* aL = aH + AL_OFF;

#pragma unroll
    for (int ks = 0; ks < 4; ++ks) {
      int pa = ((ks * 4 + quad) ^ akey) * 16;
      half8 Ah = *(const half8*)(aH + pa);
      half8 Al = *(const half8*)(aL + pa);
      half8 Bh = (ks == 0) ? BcH0 : (ks == 1) ? BcH1 : (ks == 2) ? BcH2 : BcH3;
      half8 Bl = (ks == 0) ? BcL0 : (ks == 1) ? BcL1 : (ks == 2) ? BcL2 : BcL3;
      acc0 = __builtin_amdgcn_mfma_f32_16x16x32_f16(Ah, Bh, acc0, 0, 0, 0);
      acc1 = __builtin_amdgcn_mfma_f32_16x16x32_f16(Al, Bh, acc1, 0, 0, 0);
      acc2 = __builtin_amdgcn_mfma_f32_16x16x32_f16(Ah, Bl, acc2, 0, 0, 0);
    }
    BcH0 = BnH0; BcH1 = BnH1; BcH2 = BnH2; BcH3 = BnH3;
    BcL0 = BnL0; BcL1 = BnL1; BcL2 = BnL2; BcL3 = BnL3;
  }

  floatx4 fin = acc0 + (acc1 + acc2) * (1.0f / 2048.0f);

  // ---- epilogue: y-waves hand ay to x-waves (same wt,og); atan2 + store ----
  __syncthreads();
  if (xy == 1) {
#pragma unroll
    for (int r = 0; r < 4; ++r)
      sEx[((wt * 2 + og) * 16 + n16) * 16 + quad * 4 + r] = fin[r];
  }
  __syncthreads();
  if (xy == 0) {
    int o = oh * 32 + og * 16 + n16;
    float4 res;
    float* rp = (float*)&res;
#pragma unroll
    for (int r = 0; r < 4; ++r) {
      int m = quad * 4 + r;
      float ay = sEx[((wt * 2 + og) * 16 + n16) * 16 + m];
      rp[r] = atan2f(ay, fin[r]);
    }
    float* dst = out + (((size_t)(b * 64 + o) * 32 + h) * 32 + wt * 16 + quad * 4);
    *(float4*)dst = res;
  }
}

extern "C" void kernel_launch(void* const* d_in, const int* in_sizes, int n_in,
                              void* d_out, int out_size, void* d_ws, size_t ws_size,
                              hipStream_t stream) {
  const float* x = (const float*)d_in[0];
  const float* probe = (const float*)d_in[1];
  const float* outw = (const float*)d_in[2];
  char* Bg = (char*)d_ws;
  float* out = (float*)d_out;

  ring_prep_b<<<72, 256, 0, stream>>>(probe, outw, Bg);
  ring_mfma<<<256, 512, 0, stream>>>(x, Bg, out);
}

// Round 12
// 69.777 us; speedup vs baseline: 1.0013x; 1.0013x over previous
//
#include <hip/hip_runtime.h>
#include <math.h>

// Problem constants: B=4, CIN=32, COUT=64, H=W=32, K=3, pad=1

typedef _Float16 half8 __attribute__((ext_vector_type(8)));
typedef float floatx4 __attribute__((ext_vector_type(4)));

// ---------------- workspace layout ----------------
// B_f16: [var 2][tap 9][n 128][chunk p 16][16B]  = 576 KB (L2-resident)
//   n = xy*64 + o (xy: 0=cos-weights, 1=sin-weights); position p holds
//   k-chunk q = p ^ (n & 7); k = q*8 + j, c = k>>2, feat = k&3
//   var 0 = hi, var 1 = lo*2048
// NOTE (R9 failure): B-lo CANNOT be dropped — ay abs-err ~3e-3 flips the
// atan2 branch cut at the ~50 pixels with ay~0, ax<0 -> 2pi absmax.
#define B_TAP_STRIDE (128 * 256)      // 32768
#define B_VSTRIDE (9u * 128 * 256)    // 294912

__global__ __launch_bounds__(256) void ring_prep_b(
    const float* __restrict__ probe, const float* __restrict__ outw,
    char* __restrict__ Bg) {
  int i = blockIdx.x * 256 + threadIdx.x;   // 18432 threads = 72 blocks
  int p = i & 15;
  int n = (i >> 4) & 127;
  int tap = i >> 11;
  int qd = p ^ (n & 7);
  int o = n & 63;
  int xy = n >> 6;
  half8 hi, lo;
#pragma unroll
  for (int hf = 0; hf < 2; ++hf) {
    int c = qd * 2 + hf;
    int idx = (c * 64 + o) * 9 + tap;       // ((c*COUT + o)*3 + k)*3 + l
    float th = probe[idx];
    float wvv = outw[idx];
    float sth, cth, sw, cw;
    __sincosf(th, &sth, &cth);
    __sincosf(wvv, &sw, &cw);
    float c3 = cth * fmaf(4.0f * cth, cth, -3.0f);
    float s3 = sth * fmaf(-4.0f * sth, sth, 3.0f);
    float m = xy ? sw : cw;
    float v4[4] = {0.75f * m * cth, 0.75f * m * sth, 0.25f * m * c3,
                   0.25f * m * s3};
#pragma unroll
    for (int f = 0; f < 4; ++f) {
      _Float16 hv = (_Float16)v4[f];
      hi[hf * 4 + f] = hv;
      lo[hf * 4 + f] = (_Float16)((v4[f] - (float)hv) * 2048.0f);
    }
  }
  size_t off = (((size_t)tap * 128 + n) * 16 + p) * 16;
  *(half8*)(Bg + off) = hi;
  *(half8*)(Bg + off + B_VSTRIDE) = lo;
}

// Block: one full (b,h) pixel row (32 px) x 64 n. 512 threads = 8 waves:
// wave wv -> wt = wv>>2 (pixel half), xy = (wv>>1)&1, og = wv&1.
// A-tile features (fp16 hi + lo*2048) computed in-block into swizzled LDS:
// sA [var 2][r 3][colidx 34][p 16][16B]; chunk q = p ^ (colidx & 7).
// B (hi+lo) read from global/L2 with a 2-TAP-DEEP register pipeline
// (grid = 256 = 1 block/CU -> VGPRs up to 256 are free; ~+32 VGPR).
#define AL_OFF 26112   // 1632 * 16

#define BLOAD(dst, base)                      \
  do {                                        \
    dst##0 = *(const half8*)((base) + p0);    \
    dst##1 = *(const half8*)((base) + p1);    \
    dst##2 = *(const half8*)((base) + p2);    \
    dst##3 = *(const half8*)((base) + p3);    \
  } while (0)

__global__ __launch_bounds__(512, 2) void ring_mfma(
    const float* __restrict__ x, const char* __restrict__ Bg,
    float* __restrict__ out) {
  __shared__ __align__(16) char sA[52224];
  __shared__ float sEx[1024];  // [wt 2][og 2][n 16][m 16]

  int blk = blockIdx.x;  // (b*32 + h)*2 + oh
  int oh = blk & 1;
  int h = (blk >> 1) & 31;
  int b = blk >> 6;
  int tid = threadIdx.x;

  int lane = tid & 63;
  int wv = tid >> 6;
  int n16 = lane & 15;
  int quad = lane >> 4;
  int wt = wv >> 2;
  int xy = (wv >> 1) & 1;
  int og = wv & 1;

  // global n this lane's B column lives at; swizzle key n&7 == n16&7 since
  // xy*64, oh*32, og*16 are all 0 mod 8.  (wt-independent.)
  int n_global = xy * 64 + oh * 32 + og * 16 + n16;
  const char* bRow = Bg + (size_t)n_global * 256;
  int bkey = n16 & 7;
  int p0 = ((0 * 4 + quad) ^ bkey) * 16;
  int p1 = ((1 * 4 + quad) ^ bkey) * 16;
  int p2 = ((2 * 4 + quad) ^ bkey) * 16;
  int p3 = ((3 * 4 + quad) ^ bkey) * 16;

  // ---- prefetch taps 0 and 1 (hi+lo) — in flight across the A-setup ----
  half8 BcH0, BcH1, BcH2, BcH3, BcL0, BcL1, BcL2, BcL3;   // tap t
  half8 BnH0, BnH1, BnH2, BnH3, BnL0, BnL1, BnL2, BnL3;   // tap t+1
  half8 BtH0, BtH1, BtH2, BtH3, BtL0, BtL1, BtL2, BtL3;   // tap t+2
  BLOAD(BcH, bRow);
  BLOAD(BcL, bRow + B_VSTRIDE);
  BLOAD(BnH, bRow + B_TAP_STRIDE);
  BLOAD(BnL, bRow + B_TAP_STRIDE + B_VSTRIDE);

  // ---- compute A tile in-block: 1632 units (3 r x 34 col x 16 p) ----
  // Constant-trip unroll: batch all scattered x loads first (one latency
  // wait), then the sincos/pack/LDS-write pass.
  {
    float xv0[4], xv1[4];
    int cc0[4], cc1[4];
    bool act[4];
    int us[4];
#pragma unroll
    for (int it = 0; it < 4; ++it) {
      int u = tid + it * 512;
      us[it] = u;
      bool inr = u < 1632;
      int p = u & 15;
      int t = u >> 4;
      int colidx = t % 34;
      int r = t / 34;
      int q = p ^ (colidx & 7);
      int hs = h + r - 1;
      int wsx = colidx - 1;
      bool valid = inr && ((unsigned)hs < 32u) && ((unsigned)wsx < 32u);
      act[it] = inr;
      cc0[it] = q * 2;
      cc1[it] = q * 2 + 1;
      int base = ((b * 32) * 32 + ((unsigned)hs < 32u ? hs : 0)) * 32 +
                 ((unsigned)wsx < 32u ? wsx : 0);
      xv0[it] = valid ? x[base + cc0[it] * 1024] : 0.0f;   // c stride = 32*32
      xv1[it] = valid ? x[base + cc1[it] * 1024] : 0.0f;
      // invalid (pad) -> p = 0 -> (cos,sin,cos3,sin3) = (1,0,1,0)
    }
#pragma unroll
    for (int it = 0; it < 4; ++it) {
      if (!act[it]) continue;
      half8 hi, lo;
      float pv2[2] = {xv0[it], xv1[it]};
#pragma unroll
      for (int hf = 0; hf < 2; ++hf) {
        float s1, c1;
        __sincosf(pv2[hf], &s1, &c1);
        float c3 = c1 * fmaf(4.0f * c1, c1, -3.0f);
        float s3 = s1 * fmaf(-4.0f * s1, s1, 3.0f);
        float v4[4] = {c1, s1, c3, s3};
#pragma unroll
        for (int f = 0; f < 4; ++f) {
          _Float16 hv = (_Float16)v4[f];
          hi[hf * 4 + f] = hv;
          lo[hf * 4 + f] = (_Float16)((v4[f] - (float)hv) * 2048.0f);
        }
      }
      *(half8*)(sA + us[it] * 16) = hi;            // var 0 section
      *(half8*)(sA + us[it] * 16 + AL_OFF) = lo;   // var 1 section
    }
  }

  floatx4 acc0 = {0.f, 0.f, 0.f, 0.f};   // Ah*Bh
  floatx4 acc1 = {0.f, 0.f, 0.f, 0.f};   // Al*Bh
  floatx4 acc2 = {0.f, 0.f, 0.f, 0.f};   // Ah*Bl

  __syncthreads();  // A tile visible; tap loop is barrier-free

#pragma unroll
  for (int tap = 0; tap < 9; ++tap) {
    // prefetch tap+2's B (hi+lo) into the third buffer
    if (tap < 7) {
      const char* bt = bRow + (size_t)(tap + 2) * B_TAP_STRIDE;
      BLOAD(BtH, bt);
      BLOAD(BtL, bt + B_VSTRIDE);
    }

    int dk = tap / 3;
    int l = tap - dk * 3;
    int colidx = wt * 16 + n16 + l;  // pixel-within-row + l; akey unchanged
    int akey = colidx & 7;           // by wt*16 since 16 % 8 == 0
    const char* aH = sA + (dk * 34 + colidx) * 256;
    const char* aL = aH + AL_OFF;

#pragma unroll
    for (int ks = 0; ks < 4; ++ks) {
      int pa = ((ks * 4 + quad) ^ akey) * 16;
      half8 Ah = *(const half8*)(aH + pa);
      half8 Al = *(const half8*)(aL + pa);
      half8 Bh = (ks == 0) ? BcH0 : (ks == 1) ? BcH1 : (ks == 2) ? BcH2 : BcH3;
      half8 Bl = (ks == 0) ? BcL0 : (ks == 1) ? BcL1 : (ks == 2) ? BcL2 : BcL3;
      acc0 = __builtin_amdgcn_mfma_f32_16x16x32_f16(Ah, Bh, acc0, 0, 0, 0);
      acc1 = __builtin_amdgcn_mfma_f32_16x16x32_f16(Al, Bh, acc1, 0, 0, 0);
      acc2 = __builtin_amdgcn_mfma_f32_16x16x32_f16(Ah, Bl, acc2, 0, 0, 0);
    }
    // rotate the 3-stage pipeline
    BcH0 = BnH0; BcH1 = BnH1; BcH2 = BnH2; BcH3 = BnH3;
    BcL0 = BnL0; BcL1 = BnL1; BcL2 = BnL2; BcL3 = BnL3;
    BnH0 = BtH0; BnH1 = BtH1; BnH2 = BtH2; BnH3 = BtH3;
    BnL0 = BtL0; BnL1 = BtL1; BnL2 = BtL2; BnL3 = BtL3;
  }

  floatx4 fin = acc0 + (acc1 + acc2) * (1.0f / 2048.0f);

  // ---- epilogue: y-waves hand ay to x-waves (same wt,og); atan2 + store ----
  __syncthreads();
  if (xy == 1) {
#pragma unroll
    for (int r = 0; r < 4; ++r)
      sEx[((wt * 2 + og) * 16 + n16) * 16 + quad * 4 + r] = fin[r];
  }
  __syncthreads();
  if (xy == 0) {
    int o = oh * 32 + og * 16 + n16;
    float4 res;
    float* rp = (float*)&res;
#pragma unroll
    for (int r = 0; r < 4; ++r) {
      int m = quad * 4 + r;
      float ay = sEx[((wt * 2 + og) * 16 + n16) * 16 + m];
      rp[r] = atan2f(ay, fin[r]);
    }
    float* dst = out + (((size_t)(b * 64 + o) * 32 + h) * 32 + wt * 16 + quad * 4);
    *(float4*)dst = res;
  }
}

extern "C" void kernel_launch(void* const* d_in, const int* in_sizes, int n_in,
                              void* d_out, int out_size, void* d_ws, size_t ws_size,
                              hipStream_t stream) {
  const float* x = (const float*)d_in[0];
  const float* probe = (const float*)d_in[1];
  const float* outw = (const float*)d_in[2];
  char* Bg = (char*)d_ws;
  float* out = (float*)d_out;

  ring_prep_b<<<72, 256, 0, stream>>>(probe, outw, Bg);
  ring_mfma<<<256, 512, 0, stream>>>(x, Bg, out);
}

// Round 13
// 68.290 us; speedup vs baseline: 1.0232x; 1.0218x over previous
//
#include <hip/hip_runtime.h>
#include <math.h>

// Problem constants: B=4, CIN=32, COUT=64, H=W=32, K=3, pad=1

typedef _Float16 half8 __attribute__((ext_vector_type(8)));
typedef float floatx4 __attribute__((ext_vector_type(4)));

// ---------------- workspace layout ----------------
// B_f16: [var 2][tap 9][kchunk 16][n 128][16B]  = 576 KB (L2-resident)
//   n = xy*64 + o (xy: 0=cos-weights, 1=sin-weights)
//   kchunk q holds k = q*8 + j; c = k>>2 = q*2 + (j>>2), feat = k&3
//   var 0 = hi, var 1 = lo*2048
// COALESCED for the MFMA wave read: lane (n16, quad) reads kchunk ks*4+quad
// at n_global*16 -> 4 contiguous 256-B segments per load inst (16 lines),
// vs the old n-major XOR layout's 64 scattered lines (R12 post-mortem:
// B loads were L1-transaction-bound, ~512 transactions/wave/tap).
// NOTE (R9 failure): B-lo CANNOT be dropped — ay abs-err ~3e-3 flips the
// atan2 branch cut at the ~50 pixels with ay~0, ax<0 -> 2pi absmax.
#define B_TAP_STRIDE (16 * 128 * 16)  // 32768
#define B_VSTRIDE (9u * 16 * 128 * 16)  // 294912

__global__ __launch_bounds__(256) void ring_prep_b(
    const float* __restrict__ probe, const float* __restrict__ outw,
    char* __restrict__ Bg) {
  int i = blockIdx.x * 256 + threadIdx.x;   // 18432 threads = 72 blocks
  int q = i & 15;                            // kchunk (no XOR)
  int n = (i >> 4) & 127;
  int tap = i >> 11;
  int o = n & 63;
  int xy = n >> 6;
  half8 hi, lo;
#pragma unroll
  for (int hf = 0; hf < 2; ++hf) {
    int c = q * 2 + hf;
    int idx = (c * 64 + o) * 9 + tap;       // ((c*COUT + o)*3 + k)*3 + l
    float th = probe[idx];
    float wvv = outw[idx];
    float sth, cth, sw, cw;
    __sincosf(th, &sth, &cth);
    __sincosf(wvv, &sw, &cw);
    float c3 = cth * fmaf(4.0f * cth, cth, -3.0f);
    float s3 = sth * fmaf(-4.0f * sth, sth, 3.0f);
    float m = xy ? sw : cw;
    float v4[4] = {0.75f * m * cth, 0.75f * m * sth, 0.25f * m * c3,
                   0.25f * m * s3};
#pragma unroll
    for (int f = 0; f < 4; ++f) {
      _Float16 hv = (_Float16)v4[f];
      hi[hf * 4 + f] = hv;
      lo[hf * 4 + f] = (_Float16)((v4[f] - (float)hv) * 2048.0f);
    }
  }
  size_t off = (((size_t)tap * 16 + q) * 128 + n) * 16;
  *(half8*)(Bg + off) = hi;
  *(half8*)(Bg + off + B_VSTRIDE) = lo;
}

// Block: one full (b,h) pixel row (32 px) x 64 n. 512 threads = 8 waves:
// wave wv -> wt = wv>>2 (pixel half), xy = (wv>>1)&1, og = wv&1.
// A-tile features (fp16 hi + lo*2048) computed in-block into swizzled LDS:
// sA [var 2][r 3][colidx 34][p 16][16B]; chunk q = p ^ (colidx & 7)
// (XOR kept on A: it breaks LDS bank aliasing for the MFMA-side reads).
// B (hi+lo) read coalesced from global/L2, 2-tap-deep register pipeline.
#define AL_OFF 26112   // 1632 * 16

#define BLOAD(dst, base)                          \
  do {                                            \
    dst##0 = *(const half8*)((base));             \
    dst##1 = *(const half8*)((base) + 8192);      \
    dst##2 = *(const half8*)((base) + 16384);     \
    dst##3 = *(const half8*)((base) + 24576);     \
  } while (0)

__global__ __launch_bounds__(512, 2) void ring_mfma(
    const float* __restrict__ x, const char* __restrict__ Bg,
    float* __restrict__ out) {
  __shared__ __align__(16) char sA[52224];
  __shared__ float sEx[1024];  // [wt 2][og 2][n 16][m 16]

  int blk = blockIdx.x;  // (b*32 + h)*2 + oh
  int oh = blk & 1;
  int h = (blk >> 1) & 31;
  int b = blk >> 6;
  int tid = threadIdx.x;

  int lane = tid & 63;
  int wv = tid >> 6;
  int n16 = lane & 15;
  int quad = lane >> 4;
  int wt = wv >> 2;
  int xy = (wv >> 1) & 1;
  int og = wv & 1;

  int n_global = xy * 64 + oh * 32 + og * 16 + n16;
  // lane base: kchunk = quad (ks=0) at this lane's n column
  const char* bLane = Bg + quad * 2048 + (size_t)n_global * 16;

  // ---- prefetch taps 0 and 1 (hi+lo) — in flight across the A-setup ----
  half8 BcH0, BcH1, BcH2, BcH3, BcL0, BcL1, BcL2, BcL3;   // tap t
  half8 BnH0, BnH1, BnH2, BnH3, BnL0, BnL1, BnL2, BnL3;   // tap t+1
  half8 BtH0, BtH1, BtH2, BtH3, BtL0, BtL1, BtL2, BtL3;   // tap t+2
  BLOAD(BcH, bLane);
  BLOAD(BcL, bLane + B_VSTRIDE);
  BLOAD(BnH, bLane + B_TAP_STRIDE);
  BLOAD(BnL, bLane + B_TAP_STRIDE + B_VSTRIDE);

  // ---- compute A tile in-block: 1632 units (3 r x 34 col x 16 p) ----
  {
    float xv0[4], xv1[4];
    bool act[4];
    int us[4];
#pragma unroll
    for (int it = 0; it < 4; ++it) {
      int u = tid + it * 512;
      us[it] = u;
      bool inr = u < 1632;
      int p = u & 15;
      int t = u >> 4;
      int colidx = t % 34;
      int r = t / 34;
      int q = p ^ (colidx & 7);
      int hs = h + r - 1;
      int wsx = colidx - 1;
      bool valid = inr && ((unsigned)hs < 32u) && ((unsigned)wsx < 32u);
      act[it] = inr;
      int base = ((b * 32) * 32 + ((unsigned)hs < 32u ? hs : 0)) * 32 +
                 ((unsigned)wsx < 32u ? wsx : 0);
      xv0[it] = valid ? x[base + (q * 2) * 1024] : 0.0f;   // c stride = 32*32
      xv1[it] = valid ? x[base + (q * 2 + 1) * 1024] : 0.0f;
      // invalid (pad) -> p = 0 -> (cos,sin,cos3,sin3) = (1,0,1,0)
    }
#pragma unroll
    for (int it = 0; it < 4; ++it) {
      if (!act[it]) continue;
      half8 hi, lo;
      float pv2[2] = {xv0[it], xv1[it]};
#pragma unroll
      for (int hf = 0; hf < 2; ++hf) {
        float s1, c1;
        __sincosf(pv2[hf], &s1, &c1);
        float c3 = c1 * fmaf(4.0f * c1, c1, -3.0f);
        float s3 = s1 * fmaf(-4.0f * s1, s1, 3.0f);
        float v4[4] = {c1, s1, c3, s3};
#pragma unroll
        for (int f = 0; f < 4; ++f) {
          _Float16 hv = (_Float16)v4[f];
          hi[hf * 4 + f] = hv;
          lo[hf * 4 + f] = (_Float16)((v4[f] - (float)hv) * 2048.0f);
        }
      }
      *(half8*)(sA + us[it] * 16) = hi;            // var 0 section
      *(half8*)(sA + us[it] * 16 + AL_OFF) = lo;   // var 1 section
    }
  }

  floatx4 acc0 = {0.f, 0.f, 0.f, 0.f};   // Ah*Bh
  floatx4 acc1 = {0.f, 0.f, 0.f, 0.f};   // Al*Bh
  floatx4 acc2 = {0.f, 0.f, 0.f, 0.f};   // Ah*Bl

  __syncthreads();  // A tile visible; tap loop is barrier-free

#pragma unroll
  for (int tap = 0; tap < 9; ++tap) {
    // prefetch tap+2's B (hi+lo) into the third buffer
    if (tap < 7) {
      const char* bt = bLane + (size_t)(tap + 2) * B_TAP_STRIDE;
      BLOAD(BtH, bt);
      BLOAD(BtL, bt + B_VSTRIDE);
    }

    int dk = tap / 3;
    int l = tap - dk * 3;
    int colidx = wt * 16 + n16 + l;  // pixel-within-row + l; akey unchanged
    int akey = colidx & 7;           // by wt*16 since 16 % 8 == 0
    const char* aH = sA + (dk * 34 + colidx) * 256;
    const char* aL = aH + AL_OFF;

#pragma unroll
    for (int ks = 0; ks < 4; ++ks) {
      int pa = ((ks * 4 + quad) ^ akey) * 16;
      half8 Ah = *(const half8*)(aH + pa);
      half8 Al = *(const half8*)(aL + pa);
      half8 Bh = (ks == 0) ? BcH0 : (ks == 1) ? BcH1 : (ks == 2) ? BcH2 : BcH3;
      half8 Bl = (ks == 0) ? BcL0 : (ks == 1) ? BcL1 : (ks == 2) ? BcL2 : BcL3;
      acc0 = __builtin_amdgcn_mfma_f32_16x16x32_f16(Ah, Bh, acc0, 0, 0, 0);
      acc1 = __builtin_amdgcn_mfma_f32_16x16x32_f16(Al, Bh, acc1, 0, 0, 0);
      acc2 = __builtin_amdgcn_mfma_f32_16x16x32_f16(Ah, Bl, acc2, 0, 0, 0);
    }
    // rotate the 3-stage pipeline (fully unrolled -> register renaming)
    BcH0 = BnH0; BcH1 = BnH1; BcH2 = BnH2; BcH3 = BnH3;
    BcL0 = BnL0; BcL1 = BnL1; BcL2 = BnL2; BcL3 = BnL3;
    BnH0 = BtH0; BnH1 = BtH1; BnH2 = BtH2; BnH3 = BtH3;
    BnL0 = BtL0; BnL1 = BtL1; BnL2 = BtL2; BnL3 = BtL3;
  }

  floatx4 fin = acc0 + (acc1 + acc2) * (1.0f / 2048.0f);

  // ---- epilogue: y-waves hand ay to x-waves (same wt,og); atan2 + store ----
  __syncthreads();
  if (xy == 1) {
#pragma unroll
    for (int r = 0; r < 4; ++r)
      sEx[((wt * 2 + og) * 16 + n16) * 16 + quad * 4 + r] = fin[r];
  }
  __syncthreads();
  if (xy == 0) {
    int o = oh * 32 + og * 16 + n16;
    float4 res;
    float* rp = (float*)&res;
#pragma unroll
    for (int r = 0; r < 4; ++r) {
      int m = quad * 4 + r;
      float ay = sEx[((wt * 2 + og) * 16 + n16) * 16 + m];
      rp[r] = atan2f(ay, fin[r]);
    }
    float* dst = out + (((size_t)(b * 64 + o) * 32 + h) * 32 + wt * 16 + quad * 4);
    *(float4*)dst = res;
  }
}

extern "C" void kernel_launch(void* const* d_in, const int* in_sizes, int n_in,
                              void* d_out, int out_size, void* d_ws, size_t ws_size,
                              hipStream_t stream) {
  const float* x = (const float*)d_in[0];
  const float* probe = (const float*)d_in[1];
  const float* outw = (const float*)d_in[2];
  char* Bg = (char*)d_ws;
  float* out = (float*)d_out;

  ring_prep_b<<<72, 256, 0, stream>>>(probe, outw, Bg);
  ring_mfma<<<256, 512, 0, stream>>>(x, Bg, out);
}